// Round 11
// baseline (1189.258 us; speedup 1.0000x reference)
//
#include <hip/hip_runtime.h>
#include <hip/hip_cooperative_groups.h>

namespace cg = cooperative_groups;

#define N_NODES 50000
#define C_FEAT  64
#define E_EDGES 800000
#define KEYS    400000          // dst*8 + t
#define NCHUNK  391             // ceil(KEYS/1024)
#define DPB     16              // dsts per conv block -> 16 MFMA rows

typedef __attribute__((ext_vector_type(8))) short short8;
typedef __attribute__((ext_vector_type(4))) float f32x4;

__device__ __forceinline__ float bf2f(unsigned short u) {
    union { unsigned int i; float f; } v; v.i = ((unsigned int)u) << 16; return v.f;
}
__device__ __forceinline__ unsigned short f2bf(float f) {
    union { float f; unsigned int i; } v; v.f = f;
    unsigned int r = v.i + 0x7fff + ((v.i >> 16) & 1);   // RNE
    return (unsigned short)(r >> 16);
}

// ================= cooperative aux: prep + hist + scan + scatter =================
struct AuxParams {
    const float *x, *W1, *W2;
    const int *src, *dst, *tix;
    unsigned short *xb, *WT1, *WT2;
    int *cnt, *bsum, *elist;
};

__global__ __launch_bounds__(256, 8) void aux(AuxParams p) {
    cg::grid_group grid = cg::this_grid();
    __shared__ int wsum[4];
    const int tid = threadIdx.x;
    const int lane = tid & 63;
    const int wave = tid >> 6;
    const int bid = blockIdx.x;
    const int nblocks = gridDim.x;
    const int gsz = nblocks * 256;
    const int gtid = bid * 256 + tid;

    // ---- P0: xb = bf16(x) (vec8), WT transposes, zero cnt ----
    for (int i = gtid; i < (N_NODES * 64) / 8; i += gsz) {
        int base = i * 8;
        float4 a = *(const float4*)(p.x + base);
        float4 c = *(const float4*)(p.x + base + 4);
        short8 o;
        o[0] = (short)f2bf(a.x); o[1] = (short)f2bf(a.y);
        o[2] = (short)f2bf(a.z); o[3] = (short)f2bf(a.w);
        o[4] = (short)f2bf(c.x); o[5] = (short)f2bf(c.y);
        o[6] = (short)f2bf(c.z); o[7] = (short)f2bf(c.w);
        *(short8*)(p.xb + base) = o;
    }
    for (int i = gtid; i < 32768; i += gsz) {
        int n = i >> 9, k = i & 511;
        p.WT1[i] = f2bf(p.W1[k * 64 + n]);
        p.WT2[i] = f2bf(p.W2[k * 64 + n]);
    }
    for (int i = gtid; i < KEYS / 4; i += gsz)
        ((int4*)p.cnt)[i] = make_int4(0, 0, 0, 0);
    grid.sync();

    // ---- P1: histogram over key = dst*8 + t ----
    for (int e = gtid; e < E_EDGES; e += gsz)
        atomicAdd(&p.cnt[p.dst[e] * 8 + p.tix[e]], 1);
    grid.sync();

    // ---- P2: per-chunk (1024 keys) local exclusive scan + chunk totals ----
    for (int chunk = bid; chunk < NCHUNK; chunk += nblocks) {
        const int i4 = chunk * 256 + tid;
        int4 v = make_int4(0, 0, 0, 0);
        const bool ok = (i4 * 4 < KEYS);
        if (ok) v = ((const int4*)p.cnt)[i4];
        int s = v.x + v.y + v.z + v.w;
        int sc = s;
        #pragma unroll
        for (int d = 1; d < 64; d <<= 1) {
            int o = __shfl_up(sc, d, 64);
            if (lane >= d) sc += o;
        }
        if (lane == 63) wsum[wave] = sc;
        __syncthreads();
        int wbase = 0;
        #pragma unroll
        for (int w = 0; w < 4; ++w) wbase += (w < wave) ? wsum[w] : 0;
        int tot = wsum[0] + wsum[1] + wsum[2] + wsum[3];
        __syncthreads();   // wsum reused next chunk iteration
        int base = wbase + sc - s;
        int4 o;
        o.x = base;
        o.y = base + v.x;
        o.z = o.y + v.y;
        o.w = o.z + v.z;
        if (ok) ((int4*)p.cnt)[i4] = o;
        if (tid == 0) p.bsum[chunk] = tot;
    }
    grid.sync();

    // ---- P3: chunk b adds sum(bsum[0..b)) to its 1024 keys ----
    for (int chunk = bid; chunk < NCHUNK; chunk += nblocks) {
        int s = 0;
        for (int j = tid; j < chunk; j += 256) s += p.bsum[j];
        #pragma unroll
        for (int d = 1; d < 64; d <<= 1) s += __shfl_xor(s, d, 64);
        if (lane == 0) wsum[wave] = s;
        __syncthreads();
        const int off = wsum[0] + wsum[1] + wsum[2] + wsum[3];
        __syncthreads();
        const int i4 = chunk * 256 + tid;
        if (i4 * 4 < KEYS) {
            int4 v = ((const int4*)p.cnt)[i4];
            v.x += off; v.y += off; v.z += off; v.w += off;
            ((int4*)p.cnt)[i4] = v;
        }
    }
    grid.sync();

    // ---- P4: scatter (cursor advance; afterwards cnt[k] == inclusive end) ----
    for (int e = gtid; e < E_EDGES; e += gsz) {
        int t = p.tix[e];
        int pos = atomicAdd(&p.cnt[p.dst[e] * 8 + t], 1);
        p.elist[pos] = p.src[e] | (t << 16);
    }
}

// ================= fused conv (R7/R9-proven form) =================
#define FLUSH(T, V)                                                                   \
    { int _t = (T);                                                                   \
      if (_t != cur) { scat[dl][cur * 64 + c] = f2bf(acc); acc = 0.f; cur = _t; }     \
      acc += (V); }

#define EDGE(K)                                                                       \
    int p##K = __builtin_amdgcn_readlane(pv, e + K);                                  \
    float v##K = bf2f(Xb[(size_t)(p##K & 0xffff) * 64 + c]);

__device__ __forceinline__ void gather_stage(const unsigned short* __restrict__ Xb,
                                             const int* __restrict__ segend,
                                             const int* __restrict__ elist,
                                             unsigned short (*scat)[520],
                                             int dbase, int wave, int lane) {
    const int c = lane;
    {   // zero own rows (wave-private in stage 1)
        short8 z = {};
        #pragma unroll
        for (int z4 = 0; z4 < 4; ++z4)
            *(short8*)&scat[wave * 4 + z4][lane * 8] = z;
    }
    // prefetch all 4 dsts' first windows before processing any
    int sbeg[4], send_[4], pvw[4];
    #pragma unroll
    for (int q = 0; q < 4; ++q) {
        const int d = dbase + wave * 4 + q;
        sbeg[q]  = (d == 0) ? 0 : segend[d * 8 - 1];
        send_[q] = segend[d * 8 + 7];
    }
    #pragma unroll
    for (int q = 0; q < 4; ++q)
        pvw[q] = (lane < send_[q] - sbeg[q]) ? elist[sbeg[q] + lane] : 0;

    #pragma unroll
    for (int q = 0; q < 4; ++q) {
        const int dl = wave * 4 + q;
        int i = sbeg[q];
        const int end = send_[q];
        int pv = pvw[q];
        int cur = 0;
        float acc = 0.f;
        while (i < end) {
            int cnt = end - i; cnt = (cnt > 64) ? 64 : cnt;
            int e = 0;
            for (; e + 7 < cnt; e += 8) {
                EDGE(0) EDGE(1) EDGE(2) EDGE(3) EDGE(4) EDGE(5) EDGE(6) EDGE(7)
                FLUSH(p0 >> 16, v0) FLUSH(p1 >> 16, v1)
                FLUSH(p2 >> 16, v2) FLUSH(p3 >> 16, v3)
                FLUSH(p4 >> 16, v4) FLUSH(p5 >> 16, v5)
                FLUSH(p6 >> 16, v6) FLUSH(p7 >> 16, v7)
            }
            for (; e < cnt; ++e) {
                EDGE(0)
                FLUSH(p0 >> 16, v0)
            }
            i += 64;
            if (i < end) pv = (lane < end - i) ? elist[i + lane] : 0;
        }
        scat[dl][cur * 64 + c] = f2bf(acc);   // final flush
    }
}

__global__ __launch_bounds__(256, 8) void fused_conv(const unsigned short* __restrict__ Xb,
                                                     const unsigned short* __restrict__ WT,  // [64,512] bf16
                                                     const float* __restrict__ bias,
                                                     const int* __restrict__ segend,
                                                     const int* __restrict__ elist,
                                                     float* __restrict__ H,
                                                     unsigned short* __restrict__ Hb,
                                                     int writeHb) {
    __shared__ unsigned short scat[DPB][520];
    const int lane = threadIdx.x & 63;
    const int wave = threadIdx.x >> 6;
    const int dbase = blockIdx.x * DPB;

    gather_stage(Xb, segend, elist, scat, dbase, wave, lane);
    __syncthreads();

    // MFMA [16,512]@[512,64]; C/D col=lane&15, row=quad*4+r (m89/m91; R4/R6/R7-validated)
    const int m = lane & 15;
    const int quad = lane >> 4;
    const int n0 = wave * 16;
    f32x4 acc4 = {0.f, 0.f, 0.f, 0.f};
    const unsigned short* wrow = WT + (size_t)(n0 + m) * 512;
    #pragma unroll
    for (int kc = 0; kc < 16; ++kc) {
        short8 af = *(const short8*)&scat[m][kc * 32 + quad * 8];
        short8 bf = *(const short8*)(wrow + kc * 32 + quad * 8);
        acc4 = __builtin_amdgcn_mfma_f32_16x16x32_bf16(af, bf, acc4, 0, 0, 0);
    }
    const int col = n0 + m;
    const float bcol = bias[col];
    #pragma unroll
    for (int r = 0; r < 4; ++r) {
        int node = dbase + quad * 4 + r;
        float h = fmaxf(acc4[r] + bcol, 0.f);
        H[(size_t)node * 64 + col] = h;
        if (writeHb) Hb[(size_t)node * 64 + col] = f2bf(h);
    }
}

// ================= fused adversary MLP + h1 add (f32, 64-node tiles) =================
__global__ __launch_bounds__(256) void adv_fused(const float* __restrict__ h2,
                                                 const float* __restrict__ Wa1,  // [64,128]
                                                 const float* __restrict__ ba1,  // [128]
                                                 const float* __restrict__ Wa2,  // [128,64]
                                                 const float* __restrict__ ba2,  // [64]
                                                 const float* __restrict__ h1,
                                                 float* __restrict__ out) {
    __shared__ float sH[64][68];
    __shared__ float sT[64][132];
    const int nbase = blockIdx.x * 64;
    const int tid = threadIdx.x;
    const int j0 = (tid & 15) * 4;
    const int n0 = (tid >> 4) * 4;

    #pragma unroll
    for (int i = 0; i < 4; ++i) {
        int row  = (tid >> 4) + i * 16;
        int col4 = (tid & 15);
        int node = nbase + row;
        float4 v = make_float4(0.f, 0.f, 0.f, 0.f);
        if (node < N_NODES)
            v = *(const float4*)(h2 + (size_t)node * C_FEAT + col4 * 4);
        *(float4*)&sH[row][col4 * 4] = v;
    }
    __syncthreads();

    #pragma unroll
    for (int half = 0; half < 2; ++half) {
        const int j = half * 64 + j0;
        float acc[4][4] = {};
        #pragma unroll 8
        for (int k = 0; k < 64; ++k) {
            float4 w = *(const float4*)(Wa1 + k * 128 + j);
            float a0 = sH[n0 + 0][k];
            float a1 = sH[n0 + 1][k];
            float a2 = sH[n0 + 2][k];
            float a3 = sH[n0 + 3][k];
            acc[0][0] = fmaf(a0, w.x, acc[0][0]); acc[0][1] = fmaf(a0, w.y, acc[0][1]);
            acc[0][2] = fmaf(a0, w.z, acc[0][2]); acc[0][3] = fmaf(a0, w.w, acc[0][3]);
            acc[1][0] = fmaf(a1, w.x, acc[1][0]); acc[1][1] = fmaf(a1, w.y, acc[1][1]);
            acc[1][2] = fmaf(a1, w.z, acc[1][2]); acc[1][3] = fmaf(a1, w.w, acc[1][3]);
            acc[2][0] = fmaf(a2, w.x, acc[2][0]); acc[2][1] = fmaf(a2, w.y, acc[2][1]);
            acc[2][2] = fmaf(a2, w.z, acc[2][2]); acc[2][3] = fmaf(a2, w.w, acc[2][3]);
            acc[3][0] = fmaf(a3, w.x, acc[3][0]); acc[3][1] = fmaf(a3, w.y, acc[3][1]);
            acc[3][2] = fmaf(a3, w.z, acc[3][2]); acc[3][3] = fmaf(a3, w.w, acc[3][3]);
        }
        float4 b1 = *(const float4*)(ba1 + j);
        #pragma unroll
        for (int i = 0; i < 4; ++i) {
            float4 r;
            r.x = fmaxf(acc[i][0] + b1.x, 0.f);
            r.y = fmaxf(acc[i][1] + b1.y, 0.f);
            r.z = fmaxf(acc[i][2] + b1.z, 0.f);
            r.w = fmaxf(acc[i][3] + b1.w, 0.f);
            *(float4*)&sT[n0 + i][j] = r;
        }
    }
    __syncthreads();

    float acc[4][4] = {};
    #pragma unroll 8
    for (int k = 0; k < 128; ++k) {
        float4 w = *(const float4*)(Wa2 + k * 64 + j0);
        float a0 = sT[n0 + 0][k];
        float a1 = sT[n0 + 1][k];
        float a2 = sT[n0 + 2][k];
        float a3 = sT[n0 + 3][k];
        acc[0][0] = fmaf(a0, w.x, acc[0][0]); acc[0][1] = fmaf(a0, w.y, acc[0][1]);
        acc[0][2] = fmaf(a0, w.z, acc[0][2]); acc[0][3] = fmaf(a0, w.w, acc[0][3]);
        acc[1][0] = fmaf(a1, w.x, acc[1][0]); acc[1][1] = fmaf(a1, w.y, acc[1][1]);
        acc[1][2] = fmaf(a1, w.z, acc[1][2]); acc[1][3] = fmaf(a1, w.w, acc[1][3]);
        acc[2][0] = fmaf(a2, w.x, acc[2][0]); acc[2][1] = fmaf(a2, w.y, acc[2][1]);
        acc[2][2] = fmaf(a2, w.z, acc[2][2]); acc[2][3] = fmaf(a2, w.w, acc[2][3]);
        acc[3][0] = fmaf(a3, w.x, acc[3][0]); acc[3][1] = fmaf(a3, w.y, acc[3][1]);
        acc[3][2] = fmaf(a3, w.z, acc[3][2]); acc[3][3] = fmaf(a3, w.w, acc[3][3]);
    }
    float4 b2 = *(const float4*)(ba2 + j0);
    #pragma unroll
    for (int i = 0; i < 4; ++i) {
        int node = nbase + n0 + i;
        if (node < N_NODES) {
            float4 hh = *(const float4*)(h1 + (size_t)node * C_FEAT + j0);
            float4 r;
            r.x = acc[i][0] + b2.x + hh.x;
            r.y = acc[i][1] + b2.y + hh.y;
            r.z = acc[i][2] + b2.z + hh.z;
            r.w = acc[i][3] + b2.w + hh.w;
            *(float4*)(out + (size_t)node * C_FEAT + j0) = r;
        }
    }
}

extern "C" void kernel_launch(void* const* d_in, const int* in_sizes, int n_in,
                              void* d_out, int out_size, void* d_ws, size_t ws_size,
                              hipStream_t stream) {
    const float* x   = (const float*)d_in[0];
    const int*   ei  = (const int*)d_in[1];
    const int*   tix = (const int*)d_in[2];
    const float* Wt1 = (const float*)d_in[3];
    const float* bt1 = (const float*)d_in[4];
    const float* Wt2 = (const float*)d_in[5];
    const float* bt2 = (const float*)d_in[6];
    const float* Wa1 = (const float*)d_in[7];
    const float* ba1 = (const float*)d_in[8];
    const float* Wa2 = (const float*)d_in[9];
    const float* ba2 = (const float*)d_in[10];
    float* out = (float*)d_out;

    // workspace (~44 MB)
    float* h1            = (float*)d_ws;                                  // [N,64] f32
    float* h2            = h1 + (size_t)N_NODES * 64;                     // [N,64] f32
    unsigned short* xb   = (unsigned short*)(h2 + (size_t)N_NODES * 64);  // [N,64] bf16
    unsigned short* h1b  = xb + (size_t)N_NODES * 64;                     // [N,64] bf16
    unsigned short* WT1  = h1b + (size_t)N_NODES * 64;                    // [64,512] bf16
    unsigned short* WT2  = WT1 + 64 * 512;
    int*   segend = (int*)(WT2 + 64 * 512);                               // KEYS
    int*   bsum   = segend + KEYS;                                        // 512
    int*   elist  = bsum + 512;                                           // E packed

    AuxParams ap;
    ap.x = x; ap.W1 = Wt1; ap.W2 = Wt2;
    ap.src = ei; ap.dst = ei + E_EDGES; ap.tix = tix;
    ap.xb = xb; ap.WT1 = WT1; ap.WT2 = WT2;
    ap.cnt = segend; ap.bsum = bsum; ap.elist = elist;

    int nb = 0;
    hipOccupancyMaxActiveBlocksPerMultiprocessor(&nb, (const void*)aux, 256, 0);
    if (nb < 1) nb = 1;
    if (nb > 8) nb = 8;
    void* args[] = { &ap };
    hipLaunchCooperativeKernel((const void*)aux, dim3(nb * 256), dim3(256), args, 0, stream);

    const int cBlk = N_NODES / DPB;                       // 3125 (exact)
    const int aBlk = (N_NODES + 63) / 64;                 // 782

    fused_conv<<<cBlk, 256, 0, stream>>>(xb,  WT1, bt1, segend, elist, h1, h1b, 1);
    fused_conv<<<cBlk, 256, 0, stream>>>(h1b, WT2, bt2, segend, elist, h2, h1b, 0);

    adv_fused<<<aBlk, 256, 0, stream>>>(h2, Wa1, ba1, Wa2, ba2, h1, out);
}

// Round 12
// 327.130 us; speedup vs baseline: 3.6354x; 3.6354x over previous
//
#include <hip/hip_runtime.h>

#define N_NODES 50000
#define C_FEAT  64
#define E_EDGES 800000
#define KEYS    400000          // dst*8 + t
#define NBLK1   391             // ceil(KEYS/1024)
#define DPB     16              // dsts per conv block -> 16 MFMA rows
#define PBLK_X  1563            // x->bf16 cvt blocks (8 elems/thread)
#define PBLK_W  128             // W transpose blocks
#define PBLK_H  3125            // hist blocks

typedef __attribute__((ext_vector_type(8))) short short8;
typedef __attribute__((ext_vector_type(4))) float f32x4;

__device__ __forceinline__ float bf2f(unsigned short u) {
    union { unsigned int i; float f; } v; v.i = ((unsigned int)u) << 16; return v.f;
}
__device__ __forceinline__ unsigned short f2bf(float f) {
    union { float f; unsigned int i; } v; v.f = f;
    unsigned int r = v.i + 0x7fff + ((v.i >> 16) & 1);   // RNE
    return (unsigned short)(r >> 16);
}

// ---------------- prep (x->bf16 vec8, W->WT bf16) + hist, block-range fused ----------------
__global__ __launch_bounds__(256) void prep_hist(const float* __restrict__ x,
                                                 const float* __restrict__ W1,
                                                 const float* __restrict__ W2,
                                                 const int* __restrict__ dst,
                                                 const int* __restrict__ tix,
                                                 unsigned short* __restrict__ xb,
                                                 unsigned short* __restrict__ WT1,
                                                 unsigned short* __restrict__ WT2,
                                                 int* __restrict__ cnt) {
    const int b = blockIdx.x;
    if (b < PBLK_X) {
        int base = (b * 256 + threadIdx.x) * 8;            // N*64 = 3.2M, exact
        float4 a = *(const float4*)(x + base);
        float4 c = *(const float4*)(x + base + 4);
        short8 o;
        o[0] = (short)f2bf(a.x); o[1] = (short)f2bf(a.y);
        o[2] = (short)f2bf(a.z); o[3] = (short)f2bf(a.w);
        o[4] = (short)f2bf(c.x); o[5] = (short)f2bf(c.y);
        o[6] = (short)f2bf(c.z); o[7] = (short)f2bf(c.w);
        *(short8*)(xb + base) = o;
    } else if (b < PBLK_X + PBLK_W) {
        int i = (b - PBLK_X) * 256 + threadIdx.x;          // 32768
        int n = i >> 9, k = i & 511;
        WT1[i] = f2bf(W1[k * 64 + n]);
        WT2[i] = f2bf(W2[k * 64 + n]);
    } else {
        int e = (b - PBLK_X - PBLK_W) * 256 + threadIdx.x;
        if (e < E_EDGES) atomicAdd(&cnt[dst[e] * 8 + tix[e]], 1);
    }
}

// ---------------- scan_all: per-chunk local scan; LAST block scans chunk totals ----------------
// After this kernel: cnt[k] = local exclusive prefix within its 1024-key chunk,
// chunkoff[ch] = exclusive prefix of chunk totals. Global offset = chunkoff + local.
__global__ __launch_bounds__(256) void scan_all(int* __restrict__ cnt,
                                                int* __restrict__ bsum,
                                                int* __restrict__ chunkoff,
                                                int* __restrict__ done) {
    __shared__ int wsum[4];
    __shared__ int ticket;
    const int tid = threadIdx.x;
    const int lane = tid & 63;
    const int wave = tid >> 6;
    const int i4 = blockIdx.x * 256 + tid;
    int4 v = make_int4(0, 0, 0, 0);
    const bool ok = (i4 * 4 < KEYS);                 // KEYS % 4 == 0
    if (ok) v = ((const int4*)cnt)[i4];
    int s = v.x + v.y + v.z + v.w;
    int sc = s;
    #pragma unroll
    for (int d = 1; d < 64; d <<= 1) {
        int o = __shfl_up(sc, d, 64);
        if (lane >= d) sc += o;
    }
    if (lane == 63) wsum[wave] = sc;
    __syncthreads();
    int wbase = 0;
    #pragma unroll
    for (int w = 0; w < 4; ++w) wbase += (w < wave) ? wsum[w] : 0;
    int base = wbase + sc - s;
    int4 o;
    o.x = base;
    o.y = base + v.x;
    o.z = o.y + v.y;
    o.w = o.z + v.z;
    if (ok) ((int4*)cnt)[i4] = o;
    if (tid == 255) {
        bsum[blockIdx.x] = wbase + sc;               // block total
        __threadfence();                             // bsum visible before ticket
        ticket = atomicAdd(done, 1);
    }
    __syncthreads();
    if (ticket == NBLK1 - 1 && wave == 0) {          // last-arriving block finishes
        int carry = 0;
        #pragma unroll
        for (int g = 0; g < (NBLK1 + 63) / 64; ++g) { // 7 groups
            int j = g * 64 + lane;
            int val = (j < NBLK1) ? atomicAdd(&bsum[j], 0) : 0;  // coherent read
            int scn = val;
            #pragma unroll
            for (int d = 1; d < 64; d <<= 1) {
                int oo = __shfl_up(scn, d, 64);
                if (lane >= d) scn += oo;
            }
            if (j < NBLK1) chunkoff[j] = carry + scn - val;
            carry += __shfl(scn, 63, 64);
        }
    }
}

// cursor advance on LOCAL offsets; global pos = chunkoff[chunk] + local.
// Afterwards cnt[k] == local inclusive end. elist: src | t<<16 (t-sorted per dst)
__global__ __launch_bounds__(256) void scatter_edges(const int* __restrict__ src,
                                                     const int* __restrict__ dst,
                                                     const int* __restrict__ tix,
                                                     int* __restrict__ cursor,
                                                     const int* __restrict__ chunkoff,
                                                     int* __restrict__ elist) {
    int e = blockIdx.x * 256 + threadIdx.x;
    if (e >= E_EDGES) return;
    int t = tix[e];
    int key = dst[e] * 8 + t;
    int pos = chunkoff[key >> 10] + atomicAdd(&cursor[key], 1);
    elist[pos] = src[e] | (t << 16);
}

// ---------------- fused conv: 512 threads, 8 waves x 2 dsts, bf16 FLUSH, MFMA ----------------
#define FLUSH(T, V)                                                                   \
    { int _t = (T);                                                                   \
      if (_t != cur) { scat[dl][cur * 64 + c] = f2bf(acc); acc = 0.f; cur = _t; }     \
      acc += (V); }

#define EDGE(K)                                                                       \
    int p##K = __builtin_amdgcn_readlane(pv, e + K);                                  \
    float v##K = bf2f(Xb[(size_t)(p##K & 0xffff) * 64 + c]);

__global__ __launch_bounds__(512, 4) void fused_conv(const unsigned short* __restrict__ Xb,  // [N,64] bf16
                                                     const unsigned short* __restrict__ WT,  // [64,512] bf16 (W^T)
                                                     const float* __restrict__ bias,
                                                     const int* __restrict__ segend,         // local inclusive ends
                                                     const int* __restrict__ chunkoff,       // per-1024-key offsets
                                                     const int* __restrict__ elist,          // src | t<<16
                                                     unsigned short* __restrict__ Hb) {      // [N,64] bf16
    __shared__ unsigned short scat[DPB][520];
    const int lane = threadIdx.x & 63;
    const int wave = threadIdx.x >> 6;               // 0..7
    const int dbase = blockIdx.x * DPB;
    const int c = lane;

    {   // zero own 2 rows (wave-private in stage 1)
        short8 z = {};
        *(short8*)&scat[wave * 2 + 0][lane * 8] = z;
        *(short8*)&scat[wave * 2 + 1][lane * 8] = z;
    }

    // prefetch both dsts' first windows before processing either
    int sbeg[2], send_[2], pvw[2];
    #pragma unroll
    for (int q = 0; q < 2; ++q) {
        const int d = dbase + wave * 2 + q;
        const int k0 = d * 8;
        sbeg[q]  = (d == 0) ? 0 : chunkoff[(k0 - 1) >> 10] + segend[k0 - 1];
        send_[q] = chunkoff[(k0 + 7) >> 10] + segend[k0 + 7];
    }
    #pragma unroll
    for (int q = 0; q < 2; ++q)
        pvw[q] = (lane < send_[q] - sbeg[q]) ? elist[sbeg[q] + lane] : 0;

    #pragma unroll
    for (int q = 0; q < 2; ++q) {
        const int dl = wave * 2 + q;
        int i = sbeg[q];
        const int end = send_[q];
        int pv = pvw[q];
        int cur = 0;
        float acc = 0.f;
        while (i < end) {
            int cnt = end - i; cnt = (cnt > 64) ? 64 : cnt;
            int e = 0;
            for (; e + 7 < cnt; e += 8) {
                EDGE(0) EDGE(1) EDGE(2) EDGE(3) EDGE(4) EDGE(5) EDGE(6) EDGE(7)
                FLUSH(p0 >> 16, v0) FLUSH(p1 >> 16, v1)
                FLUSH(p2 >> 16, v2) FLUSH(p3 >> 16, v3)
                FLUSH(p4 >> 16, v4) FLUSH(p5 >> 16, v5)
                FLUSH(p6 >> 16, v6) FLUSH(p7 >> 16, v7)
            }
            for (; e < cnt; ++e) {
                EDGE(0)
                FLUSH(p0 >> 16, v0)
            }
            i += 64;
            if (i < end) pv = (lane < end - i) ? elist[i + lane] : 0;
        }
        scat[dl][cur * 64 + c] = f2bf(acc);   // final flush
    }
    __syncthreads();

    // MFMA [16,512]@[512,64] on waves 0..3; C/D col=lane&15, row=quad*4+r (m89/m91)
    if (wave < 4) {
        const int m = lane & 15;
        const int quad = lane >> 4;
        const int n0 = wave * 16;
        f32x4 acc4 = {0.f, 0.f, 0.f, 0.f};
        const unsigned short* wrow = WT + (size_t)(n0 + m) * 512;
        #pragma unroll
        for (int kc = 0; kc < 16; ++kc) {
            short8 af = *(const short8*)&scat[m][kc * 32 + quad * 8];
            short8 bf = *(const short8*)(wrow + kc * 32 + quad * 8);
            acc4 = __builtin_amdgcn_mfma_f32_16x16x32_bf16(af, bf, acc4, 0, 0, 0);
        }
        const int col = n0 + m;
        const float bcol = bias[col];
        #pragma unroll
        for (int r = 0; r < 4; ++r) {
            int node = dbase + quad * 4 + r;
            Hb[(size_t)node * 64 + col] = f2bf(fmaxf(acc4[r] + bcol, 0.f));
        }
    }
}

// ---------------- fused adversary MLP + h1 add (bf16 in, f32 math, f32 out) ----------------
__global__ __launch_bounds__(256) void adv_fused(const unsigned short* __restrict__ h2b,
                                                 const float* __restrict__ Wa1,  // [64,128]
                                                 const float* __restrict__ ba1,  // [128]
                                                 const float* __restrict__ Wa2,  // [128,64]
                                                 const float* __restrict__ ba2,  // [64]
                                                 const unsigned short* __restrict__ h1b,
                                                 float* __restrict__ out) {
    __shared__ float sH[64][68];
    __shared__ float sT[64][132];
    const int nbase = blockIdx.x * 64;
    const int tid = threadIdx.x;
    const int j0 = (tid & 15) * 4;
    const int n0 = (tid >> 4) * 4;

    #pragma unroll
    for (int i = 0; i < 2; ++i) {
        int idx = tid * 2 + i;            // 512 short8 loads total
        int row = idx >> 3;
        int c8  = (idx & 7) * 8;
        int node = nbase + row;
        short8 u = {};
        if (node < N_NODES)
            u = *(const short8*)(h2b + (size_t)node * C_FEAT + c8);
        #pragma unroll
        for (int j = 0; j < 8; ++j)
            sH[row][c8 + j] = bf2f((unsigned short)u[j]);
    }
    __syncthreads();

    #pragma unroll
    for (int half = 0; half < 2; ++half) {
        const int j = half * 64 + j0;
        float acc[4][4] = {};
        #pragma unroll 8
        for (int k = 0; k < 64; ++k) {
            float4 w = *(const float4*)(Wa1 + k * 128 + j);
            float a0 = sH[n0 + 0][k];
            float a1 = sH[n0 + 1][k];
            float a2 = sH[n0 + 2][k];
            float a3 = sH[n0 + 3][k];
            acc[0][0] = fmaf(a0, w.x, acc[0][0]); acc[0][1] = fmaf(a0, w.y, acc[0][1]);
            acc[0][2] = fmaf(a0, w.z, acc[0][2]); acc[0][3] = fmaf(a0, w.w, acc[0][3]);
            acc[1][0] = fmaf(a1, w.x, acc[1][0]); acc[1][1] = fmaf(a1, w.y, acc[1][1]);
            acc[1][2] = fmaf(a1, w.z, acc[1][2]); acc[1][3] = fmaf(a1, w.w, acc[1][3]);
            acc[2][0] = fmaf(a2, w.x, acc[2][0]); acc[2][1] = fmaf(a2, w.y, acc[2][1]);
            acc[2][2] = fmaf(a2, w.z, acc[2][2]); acc[2][3] = fmaf(a2, w.w, acc[2][3]);
            acc[3][0] = fmaf(a3, w.x, acc[3][0]); acc[3][1] = fmaf(a3, w.y, acc[3][1]);
            acc[3][2] = fmaf(a3, w.z, acc[3][2]); acc[3][3] = fmaf(a3, w.w, acc[3][3]);
        }
        float4 b1 = *(const float4*)(ba1 + j);
        #pragma unroll
        for (int i = 0; i < 4; ++i) {
            float4 r;
            r.x = fmaxf(acc[i][0] + b1.x, 0.f);
            r.y = fmaxf(acc[i][1] + b1.y, 0.f);
            r.z = fmaxf(acc[i][2] + b1.z, 0.f);
            r.w = fmaxf(acc[i][3] + b1.w, 0.f);
            *(float4*)&sT[n0 + i][j] = r;
        }
    }
    __syncthreads();

    float acc[4][4] = {};
    #pragma unroll 8
    for (int k = 0; k < 128; ++k) {
        float4 w = *(const float4*)(Wa2 + k * 64 + j0);
        float a0 = sT[n0 + 0][k];
        float a1 = sT[n0 + 1][k];
        float a2 = sT[n0 + 2][k];
        float a3 = sT[n0 + 3][k];
        acc[0][0] = fmaf(a0, w.x, acc[0][0]); acc[0][1] = fmaf(a0, w.y, acc[0][1]);
        acc[0][2] = fmaf(a0, w.z, acc[0][2]); acc[0][3] = fmaf(a0, w.w, acc[0][3]);
        acc[1][0] = fmaf(a1, w.x, acc[1][0]); acc[1][1] = fmaf(a1, w.y, acc[1][1]);
        acc[1][2] = fmaf(a1, w.z, acc[1][2]); acc[1][3] = fmaf(a1, w.w, acc[1][3]);
        acc[2][0] = fmaf(a2, w.x, acc[2][0]); acc[2][1] = fmaf(a2, w.y, acc[2][1]);
        acc[2][2] = fmaf(a2, w.z, acc[2][2]); acc[2][3] = fmaf(a2, w.w, acc[2][3]);
        acc[3][0] = fmaf(a3, w.x, acc[3][0]); acc[3][1] = fmaf(a3, w.y, acc[3][1]);
        acc[3][2] = fmaf(a3, w.z, acc[3][2]); acc[3][3] = fmaf(a3, w.w, acc[3][3]);
    }
    float4 b2 = *(const float4*)(ba2 + j0);
    #pragma unroll
    for (int i = 0; i < 4; ++i) {
        int node = nbase + n0 + i;
        if (node < N_NODES) {
            const unsigned short* hp = h1b + (size_t)node * C_FEAT + j0;
            float4 r;
            r.x = acc[i][0] + b2.x + bf2f(hp[0]);
            r.y = acc[i][1] + b2.y + bf2f(hp[1]);
            r.z = acc[i][2] + b2.z + bf2f(hp[2]);
            r.w = acc[i][3] + b2.w + bf2f(hp[3]);
            *(float4*)(out + (size_t)node * C_FEAT + j0) = r;
        }
    }
}

extern "C" void kernel_launch(void* const* d_in, const int* in_sizes, int n_in,
                              void* d_out, int out_size, void* d_ws, size_t ws_size,
                              hipStream_t stream) {
    const float* x   = (const float*)d_in[0];
    const int*   ei  = (const int*)d_in[1];
    const int*   tix = (const int*)d_in[2];
    const float* Wt1 = (const float*)d_in[3];
    const float* bt1 = (const float*)d_in[4];
    const float* Wt2 = (const float*)d_in[5];
    const float* bt2 = (const float*)d_in[6];
    const float* Wa1 = (const float*)d_in[7];
    const float* ba1 = (const float*)d_in[8];
    const float* Wa2 = (const float*)d_in[9];
    const float* ba2 = (const float*)d_in[10];
    float* out = (float*)d_out;

    const int* src = ei;
    const int* dst = ei + E_EDGES;

    // workspace (~25 MB)
    unsigned short* xb   = (unsigned short*)d_ws;          // [N,64] bf16
    unsigned short* h1b  = xb + (size_t)N_NODES * 64;      // [N,64] bf16
    unsigned short* h2b  = h1b + (size_t)N_NODES * 64;     // [N,64] bf16
    unsigned short* WT1  = h2b + (size_t)N_NODES * 64;     // [64,512] bf16
    unsigned short* WT2  = WT1 + 64 * 512;
    int* cnt      = (int*)(WT2 + 64 * 512);                // KEYS
    int* bsum     = cnt + KEYS;                            // 512
    int* chunkoff = bsum + 512;                            // 512
    int* done     = chunkoff + 512;                        // 64 (1 used)
    int* elist    = done + 64;                             // E packed (src | t<<16)

    const int eBlk = (E_EDGES + 255) / 256;               // 3125
    const int cBlk = N_NODES / DPB;                       // 3125 (exact)
    const int aBlk = (N_NODES + 63) / 64;                 // 782

    // zero cnt + bsum + chunkoff + done in one memset (all rebuilt per launch)
    hipMemsetAsync(cnt, 0, (KEYS + 512 + 512 + 64) * sizeof(int), stream);
    prep_hist<<<PBLK_X + PBLK_W + PBLK_H, 256, 0, stream>>>(x, Wt1, Wt2, dst, tix,
                                                            xb, WT1, WT2, cnt);
    scan_all<<<NBLK1, 256, 0, stream>>>(cnt, bsum, chunkoff, done);
    scatter_edges<<<eBlk, 256, 0, stream>>>(src, dst, tix, cnt, chunkoff, elist);

    fused_conv<<<cBlk, 512, 0, stream>>>(xb,  WT1, bt1, cnt, chunkoff, elist, h1b);
    fused_conv<<<cBlk, 512, 0, stream>>>(h1b, WT2, bt2, cnt, chunkoff, elist, h2b);

    adv_fused<<<aBlk, 256, 0, stream>>>(h2b, Wa1, ba1, Wa2, ba2, h1b, out);
}